// Round 20
// baseline (98.133 us; speedup 1.0000x reference)
//
#include <hip/hip_runtime.h>

typedef _Float16 f16x8 __attribute__((ext_vector_type(8)));
typedef float f32x4 __attribute__((ext_vector_type(4)));

__device__ __forceinline__ unsigned short f2h(float f) {
  union { _Float16 h; unsigned short u; } v;
  v.h = (_Float16)f;
  return v.u;
}
__device__ __forceinline__ f16x8 splat8(float w) {
  _Float16 h = (_Float16)w;
  f16x8 v = {h, h, h, h, h, h, h, h};
  return v;
}

// ---------------- kernel 0: merged prep (verified R14) ----------------
__global__ __launch_bounds__(256) void prep_wx(
    const float* __restrict__ x, const float* __restrict__ w,
    unsigned short* __restrict__ xt, uint4* __restrict__ wfrag) {
  const int bid = blockIdx.x;
  const int t = threadIdx.x;
  if (bid >= 1024) {
    const int idx = (bid - 1024) * 256 + t;  // 0..73727
    const int l = idx & 63;
    const int kt = (idx >> 6) % 72;
    const int g = idx / (72 * 64);  // 0..15
    const int o = g * 16 + (l & 15);
    const int kbase = kt * 32 + ((l >> 4) * 8);
    unsigned short h[8];
#pragma unroll
    for (int e = 0; e < 8; ++e) {
      const int klin = kbase + e;
      const int kk = klin >> 8;
      const int c = klin & 255;
      h[e] = f2h(w[((size_t)o * 256 + c) * 9 + kk]);
    }
    uint4 p;
    p.x = (unsigned)h[0] | ((unsigned)h[1] << 16);
    p.y = (unsigned)h[2] | ((unsigned)h[3] << 16);
    p.z = (unsigned)h[4] | ((unsigned)h[5] << 16);
    p.w = (unsigned)h[6] | ((unsigned)h[7] << 16);
    wfrag[idx] = p;
    return;
  }
  const int b = bid >> 8;
  const int h = (bid >> 2) & 63;
  const int cq = bid & 3;
  const int wave = t >> 6, lane = t & 63;
  __shared__ float lds[64][65];
  const int wpos = t >> 2, sub = t & 3;
  const int cl0 = wave * 4 + (lane >> 4);
  const int w0 = (lane & 15) * 4;
#pragma unroll
  for (int iter = 0; iter < 4; ++iter) {
    const int cl = iter * 16 + cl0;
    const int c = cq * 64 + cl;
    float4 v = *(const float4*)(x + (((size_t)b * 256 + c) * 64 + h) * 64 + w0);
    lds[cl][w0] = v.x; lds[cl][w0 + 1] = v.y;
    lds[cl][w0 + 2] = v.z; lds[cl][w0 + 3] = v.w;
  }
  __syncthreads();
  unsigned short hb[16];
#pragma unroll
  for (int j = 0; j < 16; ++j) hb[j] = f2h(lds[sub * 16 + j][wpos]);
  uint4 p0, p1;
  p0.x = (unsigned)hb[0] | ((unsigned)hb[1] << 16);
  p0.y = (unsigned)hb[2] | ((unsigned)hb[3] << 16);
  p0.z = (unsigned)hb[4] | ((unsigned)hb[5] << 16);
  p0.w = (unsigned)hb[6] | ((unsigned)hb[7] << 16);
  p1.x = (unsigned)hb[8] | ((unsigned)hb[9] << 16);
  p1.y = (unsigned)hb[10] | ((unsigned)hb[11] << 16);
  p1.z = (unsigned)hb[12] | ((unsigned)hb[13] << 16);
  p1.w = (unsigned)hb[14] | ((unsigned)hb[15] << 16);
  unsigned short* dst = xt + (((size_t)b * 64 + h) * 64 + wpos) * 256 + cq * 64 + sub * 16;
  *(uint4*)dst = p0;
  *(uint4*)(dst + 8) = p1;
}

// ---------------- fused: wave-autonomous, ZERO barriers in main loop ---------
// block = (b, nt=h, mh). 256 thr = 4 waves = 2mg(64 rows) x 2ph(32 pos);
// each wave independently walks all 72 K32 tiles: gather taps -> combine ->
// write PRIVATE LDS B tile (within-wave lgkm ordering, no barrier) -> frag
// read -> MFMA. A direct-to-VGPR frag-major. One __syncthreads after tables.
__device__ __forceinline__ void combine8(uint4 q0, uint4 q1, uint4 q2, uint4 q3,
                                         float4 wt, uint4* dst) {
  f16x8 t0, t1, t2, t3;
  __builtin_memcpy(&t0, &q0, 16);
  __builtin_memcpy(&t1, &q1, 16);
  __builtin_memcpy(&t2, &q2, 16);
  __builtin_memcpy(&t3, &q3, 16);
  f16x8 r = t0 * splat8(wt.x);
  r += t1 * splat8(wt.y);
  r += t2 * splat8(wt.z);
  r += t3 * splat8(wt.w);
  __builtin_memcpy(dst, &r, 16);
}

__global__ __launch_bounds__(256, 2) void dcn_fused(
    const unsigned short* __restrict__ xt, const float* __restrict__ off,
    const float* __restrict__ mask, const uint4* __restrict__ wfrag,
    const float* __restrict__ bias, float* __restrict__ out) {
  __shared__ __align__(16) _Float16 Bw[4][2][1024];  // per-wave dbuf, 16 KB
  __shared__ __align__(16) float swt[9 * 64 * 4];      // 9216 B
  __shared__ __align__(16) int sidx[9 * 64 * 4];       // 9216 B

  const int bid = blockIdx.x;
  const int id = ((bid & 7) << 6) | (bid >> 3);  // bijective (512 = 8*64)
  const int b = id >> 7;
  const int nt = (id >> 1) & 63;  // h row
  const int mh = id & 1;          // M-half (rows mh*128..+127)

  const int tid = threadIdx.x;
  const int lane = tid & 63;
  const int wv = tid >> 6;   // 4 waves
  const int mg = wv >> 1;    // 64-row group within M-half
  const int ph = wv & 1;     // 32-pos half of the 64 positions
  const int lh = lane & 15, lg = lane >> 4;

  // ---- tables for all 64 positions (shared; only sync point) ----
  for (int e = tid; e < 576; e += 256) {
    const int k = e >> 6;    // 0..8
    const int pl = e & 63;   // = w
    float oy = off[(((size_t)b * 18 + 2 * k) * 64 + nt) * 64 + pl];
    float ox = off[(((size_t)b * 18 + 2 * k + 1) * 64 + nt) * 64 + pl];
    float mk = mask[(((size_t)b * 9 + k) * 64 + nt) * 64 + pl];
    float py = oy + (float)(nt - 1 + k / 3);
    float px = ox + (float)(pl - 1 + k % 3);
    float y0f = floorf(py), x0f = floorf(px);
    float ly = py - y0f, lx = px - x0f;
    float hy = 1.f - ly, hx = 1.f - lx;
    int y0 = (int)y0f, x0 = (int)x0f;
    int y1 = y0 + 1, x1 = x0 + 1;
    bool vy0 = (y0 >= 0) && (y0 < 64);
    bool vy1 = (y1 >= 0) && (y1 < 64);
    bool vx0 = (x0 >= 0) && (x0 < 64);
    bool vx1 = (x1 >= 0) && (x1 < 64);
    int yc0 = min(max(y0, 0), 63), yc1 = min(max(y1, 0), 63);
    int xc0 = min(max(x0, 0), 63), xc1 = min(max(x1, 0), 63);
    int* sp_ = sidx + (k * 64 + pl) * 4;
    float* wp = swt + (k * 64 + pl) * 4;
    sp_[0] = (yc0 * 64 + xc0) * 256;
    sp_[1] = (yc0 * 64 + xc1) * 256;
    sp_[2] = (yc1 * 64 + xc0) * 256;
    sp_[3] = (yc1 * 64 + xc1) * 256;
    wp[0] = (vy0 && vx0) ? hy * hx * mk : 0.f;
    wp[1] = (vy0 && vx1) ? hy * lx * mk : 0.f;
    wp[2] = (vy1 && vx0) ? ly * hx * mk : 0.f;
    wp[3] = (vy1 && vx1) ? ly * lx * mk : 0.f;
  }
  __syncthreads();  // tables ready; waves free-run from here

  // ---- per-lane geometry ----
  const int sp = lane >> 1;          // pos-in-32
  const int ch2 = lane & 1;          // channel-pair selector
  const int cg0 = ch2 * 2;           // 16B channel groups cg0, cg0+1
  const int gpos = ph * 32 + sp;     // pos-in-64
  const unsigned short* xtb = xt + (size_t)b * 1048576;

  // A: frag-major; wave owns row-groups mh*8+mg*4 .. +3
  const uint4* aBase = wfrag + (size_t)(mh * 8 + mg * 4) * 4608 + lane;

  // private B addrs (elements), R14-verified XOR swizzle
  _Float16* bw = &Bw[wv][0][0];
  const int wr0 = sp * 32 + ((cg0 ^ ((sp >> 1) & 3)) * 8);
  const int wr1 = sp * 32 + (((cg0 + 1) ^ ((sp >> 1) & 3)) * 8);
  const int rd0 = (0 * 16 + lh) * 32 + ((lg ^ ((lh >> 1) & 3)) * 8);
  const int rd1 = (1 * 16 + lh) * 32 + ((lg ^ ((lh >> 1) & 3)) * 8);

#define LOADTAPS(T, Q)                                                             \
  do {                                                                             \
    int4 ix = *(const int4*)(sidx + (((T) >> 3) * 64 + gpos) * 4);                 \
    const int co = ((T) & 7) * 32;                                                 \
    Q[0] = *(const uint4*)(xtb + ix.x + co + cg0 * 8);                             \
    Q[1] = *(const uint4*)(xtb + ix.y + co + cg0 * 8);                             \
    Q[2] = *(const uint4*)(xtb + ix.z + co + cg0 * 8);                             \
    Q[3] = *(const uint4*)(xtb + ix.w + co + cg0 * 8);                             \
    Q[4] = *(const uint4*)(xtb + ix.x + co + cg0 * 8 + 8);                         \
    Q[5] = *(const uint4*)(xtb + ix.y + co + cg0 * 8 + 8);                         \
    Q[6] = *(const uint4*)(xtb + ix.z + co + cg0 * 8 + 8);                         \
    Q[7] = *(const uint4*)(xtb + ix.w + co + cg0 * 8 + 8);                         \
  } while (0)

#define LOADA(T, AR)                                                               \
  do {                                                                             \
    _Pragma("unroll") for (int j = 0; j < 4; ++j)                                  \
        AR[j] = aBase[(size_t)(j * 4608 + (T) * 64)];                              \
  } while (0)

  // iter body: loads for T+1 first (max slack), combine taps(T), private-LDS
  // round trip, MFMA(T). BUF = T&1 (dbuf); within-wave DS ordering only.
#define ITER(T, QC, QL, AC, AL, DOLOAD)                                            \
  do {                                                                             \
    if (DOLOAD) {                                                                  \
      LOADTAPS((T) + 1, QL);                                                       \
      LOADA((T) + 1, AL);                                                          \
    }                                                                              \
    float4 wt4 = *(const float4*)(swt + (((T) >> 3) * 64 + gpos) * 4);             \
    uint4 r0, r1;                                                                  \
    combine8(QC[0], QC[1], QC[2], QC[3], wt4, &r0);                                \
    combine8(QC[4], QC[5], QC[6], QC[7], wt4, &r1);                                \
    _Float16* bb = bw + ((T) & 1) * 1024;                                          \
    *(uint4*)(bb + wr0) = r0;                                                      \
    *(uint4*)(bb + wr1) = r1;                                                      \
    f16x8 fr0 = *(const f16x8*)(bb + rd0);                                         \
    f16x8 fr1 = *(const f16x8*)(bb + rd1);                                         \
    __builtin_amdgcn_s_setprio(1);                                                 \
    _Pragma("unroll") for (int j = 0; j < 4; ++j) {                                \
      acc[j][0] = __builtin_amdgcn_mfma_f32_16x16x32_f16(                          \
          *(const f16x8*)&AC[j], fr0, acc[j][0], 0, 0, 0);                         \
      acc[j][1] = __builtin_amdgcn_mfma_f32_16x16x32_f16(                          \
          *(const f16x8*)&AC[j], fr1, acc[j][1], 0, 0, 0);                         \
    }                                                                              \
    __builtin_amdgcn_s_setprio(0);                                                 \
  } while (0)

  f32x4 acc[4][2] = {};
  uint4 qE[8], qO[8], AE[4], AO[4];

  // prologue: taps(0), A(0) -> even regs
  LOADTAPS(0, qE);
  LOADA(0, AE);

  for (int p = 0; p < 69; p += 2) {
    ITER(p, qE, qO, AE, AO, 1);       // even: consumes E, loads O
    ITER(p + 1, qO, qE, AO, AE, 1);   // odd: consumes O, loads E
  }
  // p ran 0..68 -> iters 0..69 done; qE=taps(70), AE=A(70)
  ITER(70, qE, qO, AE, AO, 1);        // loads taps(71), A(71) -> O
  ITER(71, qO, qE, AO, AE, 0);        // final, no loads

  // ---- epilogue ----
  float* outb = out + (size_t)b * 1048576 + (size_t)nt * 64 + ph * 32;
#pragma unroll
  for (int j = 0; j < 4; ++j) {
#pragma unroll
    for (int i = 0; i < 4; ++i) {
      const int o = (mh * 8 + mg * 4 + j) * 16 + lg * 4 + i;
      const float bs = bias[o];
      float* orow = outb + (size_t)o * 4096 + lh;
#pragma unroll
      for (int fn = 0; fn < 2; ++fn) orow[fn * 16] = acc[j][fn][i] + bs;
    }
  }
#undef LOADTAPS
#undef LOADA
#undef ITER
}

extern "C" void kernel_launch(void* const* d_in, const int* in_sizes, int n_in,
                              void* d_out, int out_size, void* d_ws, size_t ws_size,
                              hipStream_t stream) {
  const float* x = (const float*)d_in[0];
  const float* off = (const float*)d_in[1];
  const float* mask = (const float*)d_in[2];
  const float* wgt = (const float*)d_in[3];
  const float* bias = (const float*)d_in[4];
  float* out = (float*)d_out;

  uint4* wfrag = (uint4*)d_ws;                              // 73728*16B = 1.18 MB
  unsigned short* xtp = (unsigned short*)(wfrag + 73728);   // 8.4 MB

  prep_wx<<<1312, 256, 0, stream>>>(x, wgt, xtp, wfrag);
  dcn_fused<<<512, 256, 0, stream>>>(xtp, off, mask, wfrag, bias, out);
}

// Round 21
// 45.232 us; speedup vs baseline: 2.1696x; 2.1696x over previous
//
#include <hip/hip_runtime.h>

typedef _Float16 f16x8 __attribute__((ext_vector_type(8)));
typedef float f32x4 __attribute__((ext_vector_type(4)));

__device__ __forceinline__ unsigned short f2h(float f) {
  union { _Float16 h; unsigned short u; } v;
  v.h = (_Float16)f;
  return v.u;
}
__device__ __forceinline__ f16x8 splat8(float w) {
  _Float16 h = (_Float16)w;
  f16x8 v = {h, h, h, h, h, h, h, h};
  return v;
}

// ---------------- kernel 0: merged prep ----------------
// bid < 1024 : x NCHW f32 -> NHWC f16 xt[b][h][w][c]
// bid >= 1024: weight f32 [O][C][9] -> FRAG-MAJOR f16 wfrag[g][kt][lane][8]
//   g=row-group (o>>4), kt=K-tile of 32 (K=kk*256+c ordering), lane holds
//   A[o = g*16+(lane&15)][k = kt*32+(lane>>4)*8 + e], e=0..7. One uint4/slot.
__global__ __launch_bounds__(256) void prep_wx(
    const float* __restrict__ x, const float* __restrict__ w,
    unsigned short* __restrict__ xt, uint4* __restrict__ wfrag) {
  const int bid = blockIdx.x;
  const int t = threadIdx.x;
  if (bid >= 1024) {
    const int idx = (bid - 1024) * 256 + t;  // 0..73727
    const int l = idx & 63;
    const int kt = (idx >> 6) % 72;
    const int g = idx / (72 * 64);  // 0..15
    const int o = g * 16 + (l & 15);
    const int kbase = kt * 32 + ((l >> 4) * 8);
    unsigned short h[8];
#pragma unroll
    for (int e = 0; e < 8; ++e) {
      const int klin = kbase + e;
      const int kk = klin >> 8;
      const int c = klin & 255;
      h[e] = f2h(w[((size_t)o * 256 + c) * 9 + kk]);
    }
    uint4 p;
    p.x = (unsigned)h[0] | ((unsigned)h[1] << 16);
    p.y = (unsigned)h[2] | ((unsigned)h[3] << 16);
    p.z = (unsigned)h[4] | ((unsigned)h[5] << 16);
    p.w = (unsigned)h[6] | ((unsigned)h[7] << 16);
    wfrag[idx] = p;
    return;
  }
  const int b = bid >> 8;
  const int h = (bid >> 2) & 63;
  const int cq = bid & 3;
  const int wave = t >> 6, lane = t & 63;
  __shared__ float lds[64][65];
  const int wpos = t >> 2, sub = t & 3;
  const int cl0 = wave * 4 + (lane >> 4);
  const int w0 = (lane & 15) * 4;
#pragma unroll
  for (int iter = 0; iter < 4; ++iter) {
    const int cl = iter * 16 + cl0;
    const int c = cq * 64 + cl;
    float4 v = *(const float4*)(x + (((size_t)b * 256 + c) * 64 + h) * 64 + w0);
    lds[cl][w0] = v.x; lds[cl][w0 + 1] = v.y;
    lds[cl][w0 + 2] = v.z; lds[cl][w0 + 3] = v.w;
  }
  __syncthreads();
  unsigned short hb[16];
#pragma unroll
  for (int j = 0; j < 16; ++j) hb[j] = f2h(lds[sub * 16 + j][wpos]);
  uint4 p0, p1;
  p0.x = (unsigned)hb[0] | ((unsigned)hb[1] << 16);
  p0.y = (unsigned)hb[2] | ((unsigned)hb[3] << 16);
  p0.z = (unsigned)hb[4] | ((unsigned)hb[5] << 16);
  p0.w = (unsigned)hb[6] | ((unsigned)hb[7] << 16);
  p1.x = (unsigned)hb[8] | ((unsigned)hb[9] << 16);
  p1.y = (unsigned)hb[10] | ((unsigned)hb[11] << 16);
  p1.z = (unsigned)hb[12] | ((unsigned)hb[13] << 16);
  p1.w = (unsigned)hb[14] | ((unsigned)hb[15] << 16);
  unsigned short* dst = xt + (((size_t)b * 64 + h) * 64 + wpos) * 256 + cq * 64 + sub * 16;
  *(uint4*)dst = p0;
  *(uint4*)(dst + 8) = p1;
}

// ---------------- fused: A direct-to-VGPR (frag-major), lgkm-only barriers ----
// block = (b, nt=h). Out tile [256 o][64 hw]. 36 phases of K=64.
// 512 thr = 8 waves; each wave owns 32 rows (wv*32..wv*32+31): fm=2 x fn=4
// x 2 k-subtiles = 16 MFMA/phase/wave. LDS holds ONLY B ring (2x8KB) + tables.
// NO global_load_lds, NO vmcnt at barriers — A and taps certified by per-wave
// compiler-counted vmcnt.
__device__ __forceinline__ void combine8(uint4 q0, uint4 q1, uint4 q2, uint4 q3,
                                         float4 wt, _Float16* dst) {
  f16x8 t0, t1, t2, t3;
  __builtin_memcpy(&t0, &q0, 16);
  __builtin_memcpy(&t1, &q1, 16);
  __builtin_memcpy(&t2, &q2, 16);
  __builtin_memcpy(&t3, &q3, 16);
  f16x8 r = t0 * splat8(wt.x);
  r += t1 * splat8(wt.y);
  r += t2 * splat8(wt.z);
  r += t3 * splat8(wt.w);
  __builtin_memcpy(dst, &r, 16);
}

__global__ __launch_bounds__(512, 2) void dcn_fused(
    const unsigned short* __restrict__ xt, const float* __restrict__ off,
    const float* __restrict__ mask, const uint4* __restrict__ wfrag,
    const float* __restrict__ bias, float* __restrict__ out) {
  __shared__ __align__(16) _Float16 Bs[2][4096];  // 16 KB ring
  __shared__ __align__(16) float swt[9 * 64 * 4];   // 9216 B
  __shared__ __align__(16) int sidx[9 * 64 * 4];    // 9216 B

  const int bid = blockIdx.x;
  const int id = ((bid & 7) << 5) | (bid >> 3);  // XCD-contiguous, bijective
  const int b = id >> 6;
  const int nt = id & 63;  // h row

  const int tid = threadIdx.x;
  const int lane = tid & 63;
  const int wv = tid >> 6;  // 8 waves; wave owns rows wv*32..wv*32+31
  const int lh = lane & 15, lg = lane >> 4;

  // ---- precompute per-(pos,k) tap weights & indices ----
  for (int pair = tid; pair < 576; pair += 512) {
    const int k = pair >> 6;   // 0..8
    const int pl = pair & 63;  // = w
    float oy = off[(((size_t)b * 18 + 2 * k) * 64 + nt) * 64 + pl];
    float ox = off[(((size_t)b * 18 + 2 * k + 1) * 64 + nt) * 64 + pl];
    float m = mask[(((size_t)b * 9 + k) * 64 + nt) * 64 + pl];
    float py = oy + (float)(nt - 1 + k / 3);
    float px = ox + (float)(pl - 1 + k % 3);
    float y0f = floorf(py), x0f = floorf(px);
    float ly = py - y0f, lx = px - x0f;
    float hy = 1.f - ly, hx = 1.f - lx;
    int y0 = (int)y0f, x0 = (int)x0f;
    int y1 = y0 + 1, x1 = x0 + 1;
    bool vy0 = (y0 >= 0) && (y0 < 64);
    bool vy1 = (y1 >= 0) && (y1 < 64);
    bool vx0 = (x0 >= 0) && (x0 < 64);
    bool vx1 = (x1 >= 0) && (x1 < 64);
    int yc0 = min(max(y0, 0), 63), yc1 = min(max(y1, 0), 63);
    int xc0 = min(max(x0, 0), 63), xc1 = min(max(x1, 0), 63);
    int* sp = sidx + (k * 64 + pl) * 4;
    float* wp = swt + (k * 64 + pl) * 4;
    sp[0] = (yc0 * 64 + xc0) * 256;
    sp[1] = (yc0 * 64 + xc1) * 256;
    sp[2] = (yc1 * 64 + xc0) * 256;
    sp[3] = (yc1 * 64 + xc1) * 256;
    wp[0] = (vy0 && vx0) ? hy * hx * m : 0.f;
    wp[1] = (vy0 && vx1) ? hy * lx * m : 0.f;
    wp[2] = (vy1 && vx0) ? ly * hx * m : 0.f;
    wp[3] = (vy1 && vx1) ? ly * lx * m : 0.f;
  }

  // ---- A geometry: coalesced frag-major loads; wave owns groups wv*2, wv*2+1 ----
  const uint4* aBase = wfrag + (size_t)(wv * 2) * 72 * 64 + lane;

  // ---- B build geometry (identical to R12, verified) ----
  const int pos = tid >> 3, ci = tid & 7;
  const unsigned short* xtb = xt + (size_t)b * 1048576 + ci * 8;
  const int bsw = (ci >> 2) * 2048 + pos * 32 + (((ci & 3) ^ ((pos >> 1) & 3)) * 8);

  // ---- MFMA B-fragment offsets ----
  const int csw = (lg ^ ((lh >> 1) & 3)) * 8;
  int boff[4];
#pragma unroll
  for (int fn = 0; fn < 4; ++fn) boff[fn] = (fn * 16 + lh) * 32 + csw;

  // AR[j]: j&1 = row-group (fm), j>>1 = k-subtile. Max elem index:
  // (15*72 + 71)*64 + 63 = 73727 < 73728 (in-bounds).
#define LOADA(P, AR)                                                               \
  do {                                                                             \
    _Pragma("unroll") for (int j = 0; j < 4; ++j)                                  \
        AR[j] = aBase[(size_t)((((j & 1) * 72) + 2 * (P) + (j >> 1)) * 64)];       \
  } while (0)

#define LOADTAPS(Q0, Q1, Q2, Q3, IX, CO)                                           \
  do {                                                                             \
    Q0 = *(const uint4*)(xtb + (IX).x + (CO));                                     \
    Q1 = *(const uint4*)(xtb + (IX).y + (CO));                                     \
    Q2 = *(const uint4*)(xtb + (IX).z + (CO));                                     \
    Q3 = *(const uint4*)(xtb + (IX).w + (CO));                                     \
  } while (0)

#define MFMA_PHASE(BUF, AR)                                                        \
  do {                                                                             \
    const _Float16* Bb = &Bs[BUF][0];                                              \
    f16x8 b0[4], b1[4];                                                            \
    _Pragma("unroll") for (int fn = 0; fn < 4; ++fn) {                             \
      b0[fn] = *(const f16x8*)(Bb + boff[fn]);                                     \
      b1[fn] = *(const f16x8*)(Bb + 2048 + boff[fn]);                              \
    }                                                                              \
    __builtin_amdgcn_s_setprio(1);                                                 \
    _Pragma("unroll") for (int fm = 0; fm < 2; ++fm)                               \
        _Pragma("unroll") for (int fn = 0; fn < 4; ++fn) {                         \
      acc[fm][fn] = __builtin_amdgcn_mfma_f32_16x16x32_f16(                        \
          *(const f16x8*)&AR[fm], b0[fn], acc[fm][fn], 0, 0, 0);                   \
      acc[fm][fn] = __builtin_amdgcn_mfma_f32_16x16x32_f16(                        \
          *(const f16x8*)&AR[2 + fm], b1[fn], acc[fm][fn], 0, 0, 0);               \
    }                                                                              \
    __builtin_amdgcn_s_setprio(0);                                                 \
  } while (0)

#define BAR()                                                                      \
  do {                                                                             \
    asm volatile("s_waitcnt lgkmcnt(0)" ::: "memory");                             \
    __builtin_amdgcn_sched_barrier(0);                                             \
    __builtin_amdgcn_s_barrier();                                                  \
    __builtin_amdgcn_sched_barrier(0);                                             \
  } while (0)

  // phase p: A(p+1)->AL; taps(p+2)->QL; MFMA(p) from AC+Bs[p&1];
  // combine(taps p+1 = QC)->Bs[(p+1)&1]; BAR (lgkm only).
#define PHASE(P_, AL, AC, QL0, QL1, QL2, QL3, QC0, QC1, QC2, QC3)                  \
  do {                                                                             \
    LOADA((P_) + 1, AL);                                                           \
    int4 ix = *(const int4*)(sidx + ((((P_) + 2) >> 2) * 64 + pos) * 4);           \
    LOADTAPS(QL0, QL1, QL2, QL3, ix, (((P_) + 2) & 3) * 64);                       \
    float4 wt4 = *(const float4*)(swt + ((((P_) + 1) >> 2) * 64 + pos) * 4);       \
    MFMA_PHASE((P_) & 1, AC);                                                      \
    combine8(QC0, QC1, QC2, QC3, wt4, &Bs[((P_) + 1) & 1][0] + bsw);               \
    BAR();                                                                         \
  } while (0)

  f32x4 acc[2][4] = {};
  uint4 AE[4], AO[4];
  uint4 qA0, qA1, qA2, qA3, qB0, qB1, qB2, qB3;

  __syncthreads();  // swt/sidx ready

  // ---- prologue: combine tile 0 -> Bs[0]; A(0)->AE; taps(1)->qB ----
  {
    float4 wt0 = *(const float4*)(swt + pos * 4);
    int4 ix0 = *(const int4*)(sidx + pos * 4);
    LOADTAPS(qA0, qA1, qA2, qA3, ix0, 0);
    combine8(qA0, qA1, qA2, qA3, wt0, &Bs[0][0] + bsw);
    LOADA(0, AE);
    LOADTAPS(qB0, qB1, qB2, qB3, ix0, 64);
    BAR();
  }

  for (int p = 0; p < 34; p += 2) {
    PHASE(p, AO, AE, qA0, qA1, qA2, qA3, qB0, qB1, qB2, qB3);
    PHASE(p + 1, AE, AO, qB0, qB1, qB2, qB3, qA0, qA1, qA2, qA3);
  }
  // ---- tail: phase 34 (no tap prefetch), phase 35 (MFMA only) ----
  {
    LOADA(35, AO);
    float4 wt4 = *(const float4*)(swt + (8 * 64 + pos) * 4);
    MFMA_PHASE(0, AE);                                   // tile 34
    combine8(qB0, qB1, qB2, qB3, wt4, &Bs[1][0] + bsw);  // tile 35
    BAR();
    MFMA_PHASE(1, AO);                                   // tile 35
  }

  // ---- epilogue ----
  float* outb = out + (size_t)b * 1048576 + (size_t)nt * 64;
#pragma unroll
  for (int fm = 0; fm < 2; ++fm) {
#pragma unroll
    for (int i = 0; i < 4; ++i) {
      const int o = wv * 32 + fm * 16 + lg * 4 + i;
      const float bs = bias[o];
      float* orow = outb + (size_t)o * 4096 + lh;
#pragma unroll
      for (int fn = 0; fn < 4; ++fn) orow[fn * 16] = acc[fm][fn][i] + bs;
    }
  }
#undef LOADA
#undef LOADTAPS
#undef MFMA_PHASE
#undef BAR
#undef PHASE
}

extern "C" void kernel_launch(void* const* d_in, const int* in_sizes, int n_in,
                              void* d_out, int out_size, void* d_ws, size_t ws_size,
                              hipStream_t stream) {
  const float* x = (const float*)d_in[0];
  const float* off = (const float*)d_in[1];
  const float* mask = (const float*)d_in[2];
  const float* wgt = (const float*)d_in[3];
  const float* bias = (const float*)d_in[4];
  float* out = (float*)d_out;

  uint4* wfrag = (uint4*)d_ws;                              // 73728*16B = 1.18 MB
  unsigned short* xtp = (unsigned short*)(wfrag + 73728);   // 8.4 MB

  prep_wx<<<1312, 256, 0, stream>>>(x, wgt, xtp, wfrag);
  dcn_fused<<<256, 512, 0, stream>>>(xtp, off, mask, wfrag, bias, out);
}